// Round 4
// baseline (143.790 us; speedup 1.0000x reference)
//
#include <hip/hip_runtime.h>
#include <stdint.h>
#include <stddef.h>

// AdderNet 2D: out[n,f,i,j] = -sum_{c,kh,kw} |xpad[n,c,i+kh,j+kw] - W[f,c,kh,kw]|
// x: [16,32,56,56] f32, W: [64,32,3,3] f32, out: [16,64,56,56] f32. PAD=1, STRIDE=1.
//
// Wave = 1 output row (lane=col) x 8 filters; x via per-row buffer SRDs (HW OOB-zero
// == zero-pad semantics); w via batched s_buffer_load (scalar pipe) from transposed
// wq[c][fg][96] in ws. R4 change: 256-thread blocks (4 waves = 4 filter groups of the
// same (n,row)) to lift the 1-wave-workgroup-per-CU cap -> 28 waves/CU, 7/SIMD.

#define N_   16
#define C_   32
#define H_   56
#define F_   64
#define HW_  3136
#define FPW  8
#define NFG  8
#define ROWB 224                       // bytes per x row
#define WQ_ELTS (C_ * NFG * 96)       // 24576 floats = 96 KB in ws
#define TPB  256

typedef int    int32x4 __attribute__((ext_vector_type(4)));
typedef float  f32x16  __attribute__((ext_vector_type(16)));
typedef float  f32x8   __attribute__((ext_vector_type(8)));

__device__ float  __buf_load_f32(int32x4 srsrc, int voffset, int soffset, int aux) __asm("llvm.amdgcn.raw.buffer.load.f32");
__device__ f32x16 __sbuf_load_v16(int32x4 srsrc, int soffset, int aux) __asm("llvm.amdgcn.s.buffer.load.v16f32");
__device__ f32x8  __sbuf_load_v8 (int32x4 srsrc, int soffset, int aux) __asm("llvm.amdgcn.s.buffer.load.v8f32");

__device__ inline int32x4 make_srd(const void* p, int bytes) {
    union { const void* p; uint32_t u[2]; } a; a.p = p;
    int32x4 r;
    r.x = (int)a.u[0];
    r.y = (int)a.u[1];        // VA < 2^48, high bits 0 -> stride field 0
    r.z = bytes;              // num_records (stride==0 -> bytes)
    r.w = 0x00020000;         // raw untyped dword
    return r;
}

// wq[(c*NFG+fg)*96 + fi*9 + kk] = W[(fg*8+fi)*288 + c*9 + kk], pad [72..95]=0
__global__ __launch_bounds__(64)
void prep_w(const float* __restrict__ w, float* __restrict__ wq) {
    int idx = blockIdx.x * 64 + threadIdx.x;
    if (idx >= WQ_ELTS) return;
    int slot = idx % 96;
    int cg   = idx / 96;          // c*NFG + fg
    int c    = cg / NFG;
    int fg   = cg % NFG;
    int fi   = slot / 9;
    int kk   = slot % 9;
    float v = 0.0f;
    if (slot < 72)
        v = w[((fg * 8 + fi) * C_ + c) * 9 + kk];
    wq[idx] = v;
}

__global__ __launch_bounds__(TPB)
void adder_main(const float* __restrict__ x,
                const float* __restrict__ wq,
                float* __restrict__ out) {
    const int lane = threadIdx.x & 63;
    const int wid  = threadIdx.x >> 6;      // 0..3
    const int bid  = blockIdx.x;
    const int fgh  = bid & 1;               // which half of the filter groups
    const int bid2 = bid >> 1;
    const int row  = bid2 % H_;
    const int n    = bid2 / H_;
    const int fg   = fgh * 4 + wid;         // 0..7
    const int f0   = fg * FPW;

    const int vA = (lane - 1) * 4;   // col j-1 (lane 0 -> 0xFFFFFFFC -> HW OOB zero)
    const int vB = lane * 4;         // col j   (+soffset 4 -> col j+1)

    const int nr0 = (row >= 1)      ? ROWB : 0;   // kh=0 row validity (wave-uniform)
    const int nr2 = (row <= H_ - 2) ? ROWB : 0;   // kh=2

    // base of x row (row-1) for this n; kh adds H_, channel adds HW_
    const float* xb = x + (size_t)n * C_ * HW_ + (ptrdiff_t)(row - 1) * H_;

    const int32x4 wsrd = make_srd(wq, WQ_ELTS * 4);
    const int wgbase = fg * 96 * 4;               // byte offset of this fg's chunk

    float acc[FPW];
#pragma unroll
    for (int f = 0; f < FPW; ++f) acc[f] = 0.0f;

    float xva[9], xvb[9];

    auto load_ch = [&](int c, float* v) {
        const float* b = xb + (size_t)c * HW_;
        int32x4 s0 = make_srd(b,          nr0);
        int32x4 s1 = make_srd(b + H_,     ROWB);
        int32x4 s2 = make_srd(b + 2 * H_, nr2);
        v[0] = __buf_load_f32(s0, vA, 0, 0);
        v[1] = __buf_load_f32(s0, vB, 0, 0);
        v[2] = __buf_load_f32(s0, vB, 4, 0);
        v[3] = __buf_load_f32(s1, vA, 0, 0);
        v[4] = __buf_load_f32(s1, vB, 0, 0);
        v[5] = __buf_load_f32(s1, vB, 4, 0);
        v[6] = __buf_load_f32(s2, vA, 0, 0);
        v[7] = __buf_load_f32(s2, vB, 0, 0);
        v[8] = __buf_load_f32(s2, vB, 4, 0);
    };

    auto compute = [&](int c, const float* cur) {
        const int wb = c * (NFG * 96 * 4) + wgbase;
        f32x16 w0 = __sbuf_load_v16(wsrd, wb,       0);
        f32x16 w1 = __sbuf_load_v16(wsrd, wb + 64,  0);
        f32x16 w2 = __sbuf_load_v16(wsrd, wb + 128, 0);
        f32x16 w3 = __sbuf_load_v16(wsrd, wb + 192, 0);
        f32x8  w4 = __sbuf_load_v8 (wsrd, wb + 256, 0);
#pragma unroll
        for (int f = 0; f < FPW; ++f) {
#pragma unroll
            for (int k = 0; k < 9; ++k) {
                const int i = f * 9 + k;
                const float wv = (i < 16) ? w0[i]
                               : (i < 32) ? w1[i - 16]
                               : (i < 48) ? w2[i - 32]
                               : (i < 64) ? w3[i - 48]
                               :            w4[i - 64];
                acc[f] += fabsf(cur[k] - wv);
            }
        }
    };

    load_ch(0, xva);
    for (int c = 0; c < C_; c += 2) {
        load_ch(c + 1, xvb);          // c+1 <= 31 always (C_ even)
        compute(c, xva);
        if (c + 2 < C_) load_ch(c + 2, xva);
        compute(c + 1, xvb);
    }

    if (lane < H_) {
#pragma unroll
        for (int f = 0; f < FPW; ++f)
            out[(size_t)(n * F_ + f0 + f) * HW_ + row * H_ + lane] = -acc[f];
    }
}

extern "C" void kernel_launch(void* const* d_in, const int* in_sizes, int n_in,
                              void* d_out, int out_size, void* d_ws, size_t ws_size,
                              hipStream_t stream) {
    const float* x = (const float*)d_in[0];
    const float* w = (const float*)d_in[1];
    float* out = (float*)d_out;
    float* wqp = (float*)d_ws;    // 96 KB scratch

    prep_w<<<dim3((WQ_ELTS + 63) / 64), dim3(64), 0, stream>>>(w, wqp);
    adder_main<<<dim3(N_ * H_ * 2), dim3(TPB), 0, stream>>>(x, wqp, out);
}

// Round 5
// 78.797 us; speedup vs baseline: 1.8248x; 1.8248x over previous
//
#include <hip/hip_runtime.h>
#include <stdint.h>
#include <stddef.h>

// AdderNet 2D: out[n,f,i,j] = -sum_{c,kh,kw} |xpad[n,c,i+kh,j+kw] - W[f,c,kh,kw]|
// x: [16,32,56,56] f32, W: [64,32,3,3] f32, out: [16,64,56,56] f32. PAD=1, STRIDE=1.
//
// Wave = 1 output row (lane=col) x 8 filters; x via per-row buffer SRDs (HW OOB-zero
// == zero-pad semantics); w via batched s_buffer_load (scalar pipe) from transposed
// wq[c][fg][96] in ws. R5: 4-wave blocks for occupancy (7 blocks/CU exactly), with
// fg forced scalar via readfirstlane so s_buffer_load codegen survives (R4 lesson:
// wid-derived soffset looks divergent -> LLVM demotes SMEM to VMEM, SGPR 112->48).

#define N_   16
#define C_   32
#define H_   56
#define F_   64
#define HW_  3136
#define FPW  8
#define NFG  8
#define ROWB 224                       // bytes per x row
#define WQ_ELTS (C_ * NFG * 96)       // 24576 floats = 96 KB in ws
#define TPB  256

typedef int    int32x4 __attribute__((ext_vector_type(4)));
typedef float  f32x16  __attribute__((ext_vector_type(16)));
typedef float  f32x8   __attribute__((ext_vector_type(8)));

__device__ float  __buf_load_f32(int32x4 srsrc, int voffset, int soffset, int aux) __asm("llvm.amdgcn.raw.buffer.load.f32");
__device__ f32x16 __sbuf_load_v16(int32x4 srsrc, int soffset, int aux) __asm("llvm.amdgcn.s.buffer.load.v16f32");
__device__ f32x8  __sbuf_load_v8 (int32x4 srsrc, int soffset, int aux) __asm("llvm.amdgcn.s.buffer.load.v8f32");

__device__ inline int32x4 make_srd(const void* p, int bytes) {
    union { const void* p; uint32_t u[2]; } a; a.p = p;
    int32x4 r;
    r.x = (int)a.u[0];
    r.y = (int)a.u[1];        // VA < 2^48, high bits 0 -> stride field 0
    r.z = bytes;              // num_records (stride==0 -> bytes)
    r.w = 0x00020000;         // raw untyped dword
    return r;
}

// wq[(c*NFG+fg)*96 + fi*9 + kk] = W[(fg*8+fi)*288 + c*9 + kk], pad [72..95]=0
__global__ __launch_bounds__(64)
void prep_w(const float* __restrict__ w, float* __restrict__ wq) {
    int idx = blockIdx.x * 64 + threadIdx.x;
    if (idx >= WQ_ELTS) return;
    int slot = idx % 96;
    int cg   = idx / 96;          // c*NFG + fg
    int c    = cg / NFG;
    int fg   = cg % NFG;
    int fi   = slot / 9;
    int kk   = slot % 9;
    float v = 0.0f;
    if (slot < 72)
        v = w[((fg * 8 + fi) * C_ + c) * 9 + kk];
    wq[idx] = v;
}

__global__ __launch_bounds__(TPB)
void adder_main(const float* __restrict__ x,
                const float* __restrict__ wq,
                float* __restrict__ out) {
    const int lane = threadIdx.x & 63;
    const int wid  = threadIdx.x >> 6;      // 0..3 (wave-uniform)
    const int bid  = blockIdx.x;
    const int fgh  = bid & 1;               // which half of the filter groups
    const int bid2 = bid >> 1;
    const int row  = bid2 % H_;
    const int n    = bid2 / H_;
    // Force scalar: wid IS wave-uniform but the compiler can't prove it.
    const int fg   = __builtin_amdgcn_readfirstlane(fgh * 4 + wid);  // 0..7
    const int f0   = fg * FPW;

    const int vA = (lane - 1) * 4;   // col j-1 (lane 0 -> 0xFFFFFFFC -> HW OOB zero)
    const int vB = lane * 4;         // col j   (+soffset 4 -> col j+1)

    const int nr0 = (row >= 1)      ? ROWB : 0;   // kh=0 row validity (wave-uniform)
    const int nr2 = (row <= H_ - 2) ? ROWB : 0;   // kh=2

    // base of x row (row-1) for this n; kh adds H_, channel adds HW_
    const float* xb = x + (size_t)n * C_ * HW_ + (ptrdiff_t)(row - 1) * H_;

    const int32x4 wsrd = make_srd(wq, WQ_ELTS * 4);
    const int wgbase = fg * 96 * 4;               // byte offset of this fg's chunk (scalar)

    float acc[FPW];
#pragma unroll
    for (int f = 0; f < FPW; ++f) acc[f] = 0.0f;

    float xva[9], xvb[9];

    auto load_ch = [&](int c, float* v) {
        const float* b = xb + (size_t)c * HW_;
        int32x4 s0 = make_srd(b,          nr0);
        int32x4 s1 = make_srd(b + H_,     ROWB);
        int32x4 s2 = make_srd(b + 2 * H_, nr2);
        v[0] = __buf_load_f32(s0, vA, 0, 0);
        v[1] = __buf_load_f32(s0, vB, 0, 0);
        v[2] = __buf_load_f32(s0, vB, 4, 0);
        v[3] = __buf_load_f32(s1, vA, 0, 0);
        v[4] = __buf_load_f32(s1, vB, 0, 0);
        v[5] = __buf_load_f32(s1, vB, 4, 0);
        v[6] = __buf_load_f32(s2, vA, 0, 0);
        v[7] = __buf_load_f32(s2, vB, 0, 0);
        v[8] = __buf_load_f32(s2, vB, 4, 0);
    };

    auto compute = [&](int c, const float* cur) {
        const int wb = c * (NFG * 96 * 4) + wgbase;   // scalar chain
        f32x16 w0 = __sbuf_load_v16(wsrd, wb,       0);
        f32x16 w1 = __sbuf_load_v16(wsrd, wb + 64,  0);
        f32x16 w2 = __sbuf_load_v16(wsrd, wb + 128, 0);
        f32x16 w3 = __sbuf_load_v16(wsrd, wb + 192, 0);
        f32x8  w4 = __sbuf_load_v8 (wsrd, wb + 256, 0);
#pragma unroll
        for (int f = 0; f < FPW; ++f) {
#pragma unroll
            for (int k = 0; k < 9; ++k) {
                const int i = f * 9 + k;
                const float wv = (i < 16) ? w0[i]
                               : (i < 32) ? w1[i - 16]
                               : (i < 48) ? w2[i - 32]
                               : (i < 64) ? w3[i - 48]
                               :            w4[i - 64];
                acc[f] += fabsf(cur[k] - wv);
            }
        }
    };

    load_ch(0, xva);
    for (int c = 0; c < C_; c += 2) {
        load_ch(c + 1, xvb);          // c+1 <= 31 always (C_ even)
        compute(c, xva);
        if (c + 2 < C_) load_ch(c + 2, xva);
        compute(c + 1, xvb);
    }

    if (lane < H_) {
#pragma unroll
        for (int f = 0; f < FPW; ++f)
            out[(size_t)(n * F_ + f0 + f) * HW_ + row * H_ + lane] = -acc[f];
    }
}

extern "C" void kernel_launch(void* const* d_in, const int* in_sizes, int n_in,
                              void* d_out, int out_size, void* d_ws, size_t ws_size,
                              hipStream_t stream) {
    const float* x = (const float*)d_in[0];
    const float* w = (const float*)d_in[1];
    float* out = (float*)d_out;
    float* wqp = (float*)d_ws;    // 96 KB scratch

    prep_w<<<dim3((WQ_ELTS + 63) / 64), dim3(64), 0, stream>>>(w, wqp);
    adder_main<<<dim3(N_ * H_ * 2), dim3(TPB), 0, stream>>>(x, wqp, out);
}